// Round 1
// baseline (1930.822 us; speedup 1.0000x reference)
//
#include <hip/hip_runtime.h>
#include <math.h>

// Problem constants (B,H,S,D) = (2,16,2048,64), fp32 in/out.
#define B_  2
#define H_  16
#define S_  2048
#define D_  64
#define QT  16            // query rows per block
#define NQT (S_/QT)       // 128 q-tiles per (b,h)

// One block = 256 threads = 4 waves. LDS: 128KB scores + 4KB Q + small.
// 1 block/CU (LDS-bound). Phases:
//   1) QK^T: per-thread acc[16][8] (thread t owns k = kc*256+t), K streamed
//      from global (each block reads its head's K exactly once, L2-resident).
//   2) scale + mask -> LDS scores.
//   3) softmax: wave w owns rows 4w..4w+3, shfl_xor reductions (no x-wave).
//   4) attn write: flat float4 coalesced, * inv_l.
//   5) PV: wave w owns rows 4w..4w+3, lane = d (coalesced V row reads,
//      broadcast LDS reads of p), ctx regs, scale by inv_l at end.
__global__ __launch_bounds__(256, 1)
void sdpa_fused_kernel(const float* __restrict__ Q, const float* __restrict__ K,
                       const float* __restrict__ V, const int* __restrict__ M,
                       float* __restrict__ ctx_out, float* __restrict__ attn_out) {
    __shared__ __align__(16) float qs[QT][D_];     // 4 KB
    __shared__ __align__(16) float sc[QT][S_];     // 128 KB
    __shared__ float linv[QT];

    const int t   = threadIdx.x;
    const int bid = blockIdx.x;
    const int bh  = bid >> 7;        // (b*H + h), 0..31
    const int qt  = bid & (NQT - 1);
    const int b   = bh >> 4;
    const int q0  = qt * QT;

    // ---- load Q tile: 16x64 = 1024 floats = 256 float4, one per thread ----
    {
        const float4* Qv = (const float4*)(Q + (size_t)bh * S_ * D_ + (size_t)q0 * D_);
        ((float4*)&qs[0][0])[t] = Qv[t];
    }
    __syncthreads();

    // ---- phase 1: QK^T into registers ----
    float acc[QT][8];
    #pragma unroll
    for (int q = 0; q < QT; ++q)
        #pragma unroll
        for (int kc = 0; kc < 8; ++kc) acc[q][kc] = 0.f;

    const float4* Kv = (const float4*)(K + (size_t)bh * S_ * D_);
    #pragma unroll 2
    for (int d4 = 0; d4 < 16; ++d4) {
        float4 kv[8];
        #pragma unroll
        for (int kc = 0; kc < 8; ++kc)
            kv[kc] = Kv[(size_t)(kc * 256 + t) * (D_ / 4) + d4];
        #pragma unroll
        for (int q = 0; q < QT; ++q) {
            const float4 qv = ((const float4*)qs[q])[d4];   // wave-uniform broadcast
            #pragma unroll
            for (int kc = 0; kc < 8; ++kc) {
                acc[q][kc] = fmaf(qv.x, kv[kc].x,
                             fmaf(qv.y, kv[kc].y,
                             fmaf(qv.z, kv[kc].z,
                             fmaf(qv.w, kv[kc].w, acc[q][kc]))));
            }
        }
    }

    // ---- phase 2: scale + mask -> LDS ----
    {
        const int* Mrow = M + (size_t)b * S_ * S_;
        #pragma unroll
        for (int q = 0; q < QT; ++q) {
            #pragma unroll
            for (int kc = 0; kc < 8; ++kc) {
                const int k  = kc * 256 + t;
                const int mk = Mrow[(size_t)(q0 + q) * S_ + k];
                sc[q][k] = mk ? acc[q][kc] * 0.125f : -1e9f;
            }
        }
    }
    __syncthreads();

    // ---- phase 3: softmax (wave w -> rows 4w..4w+3) ----
    const int w    = t >> 6;
    const int lane = t & 63;
    #pragma unroll
    for (int r = 0; r < 4; ++r) {
        const int q = w * 4 + r;
        float4* row4 = (float4*)sc[q];
        float4 vv[8];
        float m = -3.0e38f;
        #pragma unroll
        for (int i = 0; i < 8; ++i) {
            const float4 v = row4[i * 64 + lane];
            vv[i] = v;
            m = fmaxf(m, fmaxf(fmaxf(v.x, v.y), fmaxf(v.z, v.w)));
        }
        #pragma unroll
        for (int off = 32; off; off >>= 1) m = fmaxf(m, __shfl_xor(m, off));
        float s = 0.f;
        #pragma unroll
        for (int i = 0; i < 8; ++i) {
            float4 v = vv[i];
            v.x = __expf(v.x - m); v.y = __expf(v.y - m);
            v.z = __expf(v.z - m); v.w = __expf(v.w - m);
            s += (v.x + v.y) + (v.z + v.w);
            row4[i * 64 + lane] = v;
        }
        #pragma unroll
        for (int off = 32; off; off >>= 1) s += __shfl_xor(s, off);
        if (lane == 0) linv[q] = 1.0f / s;
    }
    __syncthreads();

    // ---- phase 4: write attn (16 rows x 2048 = 8192 float4, 32/thread) ----
    {
        float4* arow = (float4*)(attn_out + (size_t)bh * S_ * S_ + (size_t)q0 * S_);
        const float4* sc4 = (const float4*)&sc[0][0];
        #pragma unroll
        for (int j = 0; j < 32; ++j) {
            const int flat = j * 256 + t;        // 0..8191
            const float il = linv[flat >> 9];    // 512 float4 per row
            float4 p = sc4[flat];
            p.x *= il; p.y *= il; p.z *= il; p.w *= il;
            arow[flat] = p;
        }
    }

    // ---- phase 5: PV (wave w -> rows 4w..4w+3, lane = d) ----
    {
        const float* Vp = V + (size_t)bh * S_ * D_;
        float ctxa[4] = {0.f, 0.f, 0.f, 0.f};
        for (int k = 0; k < S_; k += 4) {
            float v0 = Vp[(k + 0) * D_ + lane];
            float v1 = Vp[(k + 1) * D_ + lane];
            float v2 = Vp[(k + 2) * D_ + lane];
            float v3 = Vp[(k + 3) * D_ + lane];
            #pragma unroll
            for (int r = 0; r < 4; ++r) {
                const float4 p = *(const float4*)&sc[w * 4 + r][k];  // broadcast
                ctxa[r] += p.x * v0 + p.y * v1 + p.z * v2 + p.w * v3;
            }
        }
        #pragma unroll
        for (int r = 0; r < 4; ++r) {
            const int q = w * 4 + r;
            ctx_out[((size_t)bh * S_ + q0 + q) * D_ + lane] = ctxa[r] * linv[q];
        }
    }
}

extern "C" void kernel_launch(void* const* d_in, const int* in_sizes, int n_in,
                              void* d_out, int out_size, void* d_ws, size_t ws_size,
                              hipStream_t stream) {
    const float* Q = (const float*)d_in[0];
    const float* K = (const float*)d_in[1];
    const float* V = (const float*)d_in[2];
    const int*   M = (const int*)d_in[3];

    float* ctx  = (float*)d_out;                                   // [B,H,S,D]
    float* attn = (float*)d_out + (size_t)B_ * H_ * S_ * D_;       // [B,H,S,S]

    sdpa_fused_kernel<<<dim3(B_ * H_ * NQT), dim3(256), 0, stream>>>(Q, K, V, M, ctx, attn);
}

// Round 2
// 456.973 us; speedup vs baseline: 4.2252x; 4.2252x over previous
//
#include <hip/hip_runtime.h>
#include <math.h>

// (B,H,S,D) = (2,16,2048,64), fp32 in/out. Outputs: ctx [B,H,S,D] ++ attn [B,H,S,S].
#define B_   2
#define H_   16
#define S_   2048
#define D_   64
#define QT   16
#define NQT  (S_/QT)        // 128
#define NBLK (B_*H_*NQT)    // 4096

typedef __attribute__((ext_vector_type(8))) short  bf16x8;
typedef __attribute__((ext_vector_type(8))) unsigned short u16x8;
typedef __attribute__((ext_vector_type(4))) float  f32x4;

static __device__ __forceinline__ short f2bf(float f) {
    union { float f; unsigned u; } x; x.f = f;
    unsigned r = x.u + 0x7fffu + ((x.u >> 16) & 1u);   // RNE
    return (short)(r >> 16);
}
static __device__ __forceinline__ float bf2f(unsigned short u) {
    union { unsigned u; float f; } x; x.u = ((unsigned)u) << 16;
    return x.f;
}

// One block = 256 thr = 4 waves handles one (bh, 16-query tile).
// LDS: sc[16][2048] bf16 (64KB, XOR-swizzled 16B units) -> 2 blocks/CU.
// Phase 1: QK^T via mfma_f32_16x16x32_bf16 (scale 0.125 folded into Q cvt),
//          mask -> bf16 scores scattered to LDS. Wave w owns keys [512w,512w+512).
// Phase 2: softmax per row (wave w owns rows 4w..4w+3): row in regs (32 f32/lane),
//          64-lane shfl reduce max/sum; write attn = exp*inv (fp32, coalesced)
//          and bf16(exp) back to LDS for PV.
// Phase 3: PV via MFMA: wave w owns d-tile [16w,16w+16); A = P from LDS
//          (swizzled ds_read_b128), B = V fp32 strided loads + cvt.
__global__ __launch_bounds__(256, 2)
void sdpa_mfma_kernel(const float* __restrict__ Q, const float* __restrict__ K,
                      const float* __restrict__ V, const int* __restrict__ M,
                      float* __restrict__ ctx_out, float* __restrict__ attn_out) {
    __shared__ __align__(16) unsigned short sc[QT][S_];   // bf16 bits, 64 KB
    __shared__ float linv[QT];

    const int t  = threadIdx.x;
    const int w  = t >> 6;
    const int l  = t & 63;
    const int lr = l & 15;        // A/B row-or-col lane field
    const int lg = l >> 4;        // k-group 0..3

    // XCD-aware swizzle: 4096 blocks, 512/XCD -> 4 heads per XCD stay L2-hot.
    const int orig = blockIdx.x;
    const int swz  = (orig & 7) * (NBLK / 8) + (orig >> 3);
    const int bh   = swz >> 7;    // 0..31
    const int qt   = swz & 127;
    const int b    = bh >> 4;
    const int q0   = qt * QT;

    const float* Qb = Q + (size_t)bh * S_ * D_;
    const float* Kb = K + (size_t)bh * S_ * D_;
    const float* Vb = V + (size_t)bh * S_ * D_;
    const int*   Mb = M + (size_t)b * S_ * S_;

    // ---- A-frags: Q rows (scale 1/8 folded; exact, pow2) ----
    bf16x8 aq0, aq1;
    {
        const float* qp = Qb + (size_t)(q0 + lr) * D_ + lg * 8;
        #pragma unroll
        for (int j = 0; j < 8; ++j) aq0[j] = f2bf(0.125f * qp[j]);
        #pragma unroll
        for (int j = 0; j < 8; ++j) aq1[j] = f2bf(0.125f * qp[32 + j]);
    }

    // ---- Phase 1: QK^T ----
    #pragma unroll 2
    for (int kt = 0; kt < 32; ++kt) {
        const int k0 = w * 512 + kt * 16;
        const float* kp = Kb + (size_t)(k0 + lr) * D_ + lg * 8;
        bf16x8 bk0, bk1;
        #pragma unroll
        for (int j = 0; j < 8; ++j) bk0[j] = f2bf(kp[j]);
        #pragma unroll
        for (int j = 0; j < 8; ++j) bk1[j] = f2bf(kp[32 + j]);
        f32x4 c = {0.f, 0.f, 0.f, 0.f};
        c = __builtin_amdgcn_mfma_f32_16x16x32_bf16(aq0, bk0, c, 0, 0, 0);
        c = __builtin_amdgcn_mfma_f32_16x16x32_bf16(aq1, bk1, c, 0, 0, 0);
        const int key = k0 + lr;                    // C col
        #pragma unroll
        for (int r = 0; r < 4; ++r) {
            const int row = lg * 4 + r;             // C row
            const int mk  = Mb[(size_t)(q0 + row) * S_ + key];
            const float s = mk ? c[r] : -1e9f;
            sc[row][(((key >> 3) ^ (row & 7)) << 3) + (key & 7)] = (unsigned short)f2bf(s);
        }
    }
    __syncthreads();

    // ---- Phase 2: softmax + attn write (wave w -> rows 4w..4w+3) ----
    #pragma unroll
    for (int r = 0; r < 4; ++r) {
        const int q = w * 4 + r;
        const int x = q & 7;
        float f[32];
        #pragma unroll
        for (int i = 0; i < 4; ++i) {
            const u16x8 u = *(const u16x8*)&sc[q][(i * 64 + l) * 8];
            #pragma unroll
            for (int j = 0; j < 8; ++j) f[i * 8 + j] = bf2f(u[j]);
        }
        float m = f[0];
        #pragma unroll
        for (int j = 1; j < 32; ++j) m = fmaxf(m, f[j]);
        #pragma unroll
        for (int off = 32; off; off >>= 1) m = fmaxf(m, __shfl_xor(m, off));
        float ssum = 0.f;
        #pragma unroll
        for (int j = 0; j < 32; ++j) { f[j] = __expf(f[j] - m); ssum += f[j]; }
        #pragma unroll
        for (int off = 32; off; off >>= 1) ssum += __shfl_xor(ssum, off);
        const float il = 1.0f / ssum;
        if (l == 0) linv[q] = il;

        float* arow = attn_out + ((size_t)bh * S_ + q0 + q) * S_;
        #pragma unroll
        for (int i = 0; i < 4; ++i) {
            const int us = i * 64 + l;              // storage unit (swizzled domain)
            u16x8 ub;
            #pragma unroll
            for (int j = 0; j < 8; ++j) ub[j] = (unsigned short)f2bf(f[i * 8 + j]);
            *(u16x8*)&sc[q][us * 8] = ub;           // exp (unnormalized) for PV
            const int uk = us ^ x;                  // key unit in global order
            float4 o0, o1;
            o0.x = f[i*8+0]*il; o0.y = f[i*8+1]*il; o0.z = f[i*8+2]*il; o0.w = f[i*8+3]*il;
            o1.x = f[i*8+4]*il; o1.y = f[i*8+5]*il; o1.z = f[i*8+6]*il; o1.w = f[i*8+7]*il;
            *(float4*)(arow + (size_t)uk * 8)     = o0;
            *(float4*)(arow + (size_t)uk * 8 + 4) = o1;
        }
    }
    __syncthreads();

    // ---- Phase 3: PV (wave w -> d-tile [16w,16w+16)) ----
    {
        const int d0 = w * 16;
        f32x4 cc = {0.f, 0.f, 0.f, 0.f};
        #pragma unroll 2
        for (int ks = 0; ks < 64; ++ks) {
            const int k0 = ks * 32;
            const int un = ((k0 >> 3) + lg) ^ (lr & 7);
            const bf16x8 pa = *(const bf16x8*)&sc[lr][un * 8];     // A: P[q=lr][k]
            const float* vp = Vb + (size_t)(k0 + lg * 8) * D_ + d0 + lr;
            bf16x8 vb;
            #pragma unroll
            for (int j = 0; j < 8; ++j) vb[j] = f2bf(vp[(size_t)j * D_]);  // B: V[k][d]
            cc = __builtin_amdgcn_mfma_f32_16x16x32_bf16(pa, vb, cc, 0, 0, 0);
        }
        #pragma unroll
        for (int r = 0; r < 4; ++r) {
            const int q = lg * 4 + r;
            ctx_out[((size_t)bh * S_ + q0 + q) * D_ + d0 + lr] = cc[r] * linv[q];
        }
    }
}

extern "C" void kernel_launch(void* const* d_in, const int* in_sizes, int n_in,
                              void* d_out, int out_size, void* d_ws, size_t ws_size,
                              hipStream_t stream) {
    const float* Q = (const float*)d_in[0];
    const float* K = (const float*)d_in[1];
    const float* V = (const float*)d_in[2];
    const int*   M = (const int*)d_in[3];

    float* ctx  = (float*)d_out;                                   // [B,H,S,D]
    float* attn = (float*)d_out + (size_t)B_ * H_ * S_ * D_;       // [B,H,S,S]

    sdpa_mfma_kernel<<<dim3(NBLK), dim3(256), 0, stream>>>(Q, K, V, M, ctx, attn);
}

// Round 3
// 374.927 us; speedup vs baseline: 5.1499x; 1.2188x over previous
//
#include <hip/hip_runtime.h>
#include <math.h>

// (B,H,S,D) = (2,16,2048,64), fp32 in/out. Outputs: ctx [B,H,S,D] ++ attn [B,H,S,S].
#define B_   2
#define H_   16
#define S_   2048
#define D_   64
#define QT   16
#define NQT  (S_/QT)        // 128
#define NBLK (B_*H_*NQT)    // 4096

typedef __attribute__((ext_vector_type(8))) short  bf16x8;
typedef __attribute__((ext_vector_type(8))) unsigned short u16x8;
typedef __attribute__((ext_vector_type(4))) float  f32x4;

static __device__ __forceinline__ short f2bf(float f) {
    union { float f; unsigned u; } x; x.f = f;
    unsigned r = x.u + 0x7fffu + ((x.u >> 16) & 1u);   // RNE
    return (short)(r >> 16);
}
static __device__ __forceinline__ float bf2f(unsigned short u) {
    union { unsigned u; float f; } x; x.u = ((unsigned)u) << 16;
    return x.f;
}

// ---------- pre-pass 1: K fp32 -> bf16 (same [bh][k][d] layout) ----------
__global__ __launch_bounds__(256) void cvtK_kernel(const float* __restrict__ K,
                                                   unsigned short* __restrict__ Kb) {
    const size_t i = ((size_t)blockIdx.x * 256 + threadIdx.x) * 8;
    const float4 a = *(const float4*)(K + i);
    const float4 b = *(const float4*)(K + i + 4);
    u16x8 o;
    o[0]=f2bf(a.x); o[1]=f2bf(a.y); o[2]=f2bf(a.z); o[3]=f2bf(a.w);
    o[4]=f2bf(b.x); o[5]=f2bf(b.y); o[6]=f2bf(b.z); o[7]=f2bf(b.w);
    *(u16x8*)(Kb + i) = o;
}

// ---------- pre-pass 2: V fp32 [bh][k][d] -> bf16 transposed Vt [bh][d][k] ----------
__global__ __launch_bounds__(256) void cvtVT_kernel(const float* __restrict__ V,
                                                    unsigned short* __restrict__ Vt) {
    const int l  = threadIdx.x & 63;
    const int w  = threadIdx.x >> 6;
    const int bh = blockIdx.x >> 6;
    const int kc = (blockIdx.x & 63) * 32 + w * 8;
    const float* vp = V + ((size_t)bh * S_ + kc) * D_ + l;   // lane = d, coalesced rows
    u16x8 o;
    #pragma unroll
    for (int j = 0; j < 8; ++j) o[j] = f2bf(vp[(size_t)j * D_]);
    *(u16x8*)(Vt + ((size_t)bh * D_ + l) * S_ + kc) = o;
}

// ---------- pre-pass 3: mask int32 -> bitmask (bit k of row q) ----------
__global__ __launch_bounds__(256) void maskbits_kernel(const int* __restrict__ M,
                                                       unsigned long long* __restrict__ bits) {
    const int w = threadIdx.x >> 6, l = threadIdx.x & 63;
    const size_t wl0 = (size_t)(blockIdx.x * 4 + w) * 32;
    for (int it = 0; it < 32; ++it) {
        const int mk = M[(wl0 + it) * 64 + l];
        const unsigned long long bm = __ballot(mk != 0);
        if (l == 0) bits[wl0 + it] = bm;
    }
}

// One block = 256 thr = 4 waves handles one (bh, 16-query tile).
// LDS: sc[16][2048] bf16 (64KB, XOR-swizzled 16B units) + 4KB mask-bit tile.
template<int PREP>
__global__ __launch_bounds__(256, 2)
void sdpa_mfma_kernel(const float* __restrict__ Q, const float* __restrict__ K,
                      const float* __restrict__ V, const int* __restrict__ M,
                      const unsigned short* __restrict__ Kb,
                      const unsigned short* __restrict__ Vt,
                      const unsigned* __restrict__ bits,
                      float* __restrict__ ctx_out, float* __restrict__ attn_out) {
    __shared__ __align__(16) unsigned short sc[QT][S_];   // bf16 bits, 64 KB
    __shared__ __align__(16) unsigned mb[QT][64];         // mask bits tile, 4 KB
    __shared__ float linv[QT];

    const int t  = threadIdx.x;
    const int w  = t >> 6;
    const int l  = t & 63;
    const int lr = l & 15;
    const int lg = l >> 4;

    const int orig = blockIdx.x;
    const int swz  = (orig & 7) * (NBLK / 8) + (orig >> 3);
    const int bh   = swz >> 7;
    const int qt   = swz & 127;
    const int b    = bh >> 4;
    const int q0   = qt * QT;

    const float* Qb = Q + (size_t)bh * S_ * D_;
    const int*   Mb = M + (size_t)b * S_ * S_;

    if (PREP) {   // cooperative 4KB mask-bit tile: rows q0..q0+15 x 2048 keys
        const int r = t >> 4, cw = (t & 15) * 4;
        *(uint4*)&mb[r][cw] = *(const uint4*)(bits + ((size_t)b * S_ + q0 + r) * 64 + cw);
    }

    // ---- A-frags: Q rows (scale 1/8 folded; exact, pow2) ----
    bf16x8 aq0, aq1;
    {
        const float* qp = Qb + (size_t)(q0 + lr) * D_ + lg * 8;
        #pragma unroll
        for (int j = 0; j < 8; ++j) aq0[j] = f2bf(0.125f * qp[j]);
        #pragma unroll
        for (int j = 0; j < 8; ++j) aq1[j] = f2bf(0.125f * qp[32 + j]);
    }
    if (PREP) __syncthreads();   // mb ready

    // ---- Phase 1: QK^T (wave w owns keys [512w, 512w+512)) ----
    #pragma unroll 2
    for (int kt = 0; kt < 32; ++kt) {
        const int k0 = w * 512 + kt * 16;
        bf16x8 bk0, bk1;
        if (PREP) {
            const unsigned short* kp = Kb + ((size_t)bh * S_ + k0 + lr) * D_ + lg * 8;
            bk0 = *(const bf16x8*)kp;
            bk1 = *(const bf16x8*)(kp + 32);
        } else {
            const float* kp = K + ((size_t)bh * S_ + k0 + lr) * D_ + lg * 8;
            #pragma unroll
            for (int j = 0; j < 8; ++j) bk0[j] = f2bf(kp[j]);
            #pragma unroll
            for (int j = 0; j < 8; ++j) bk1[j] = f2bf(kp[32 + j]);
        }
        f32x4 c = {0.f, 0.f, 0.f, 0.f};
        c = __builtin_amdgcn_mfma_f32_16x16x32_bf16(aq0, bk0, c, 0, 0, 0);
        c = __builtin_amdgcn_mfma_f32_16x16x32_bf16(aq1, bk1, c, 0, 0, 0);
        const int key = k0 + lr;                    // C col
        #pragma unroll
        for (int r = 0; r < 4; ++r) {
            const int row = lg * 4 + r;             // C row
            int mk;
            if (PREP) mk = (mb[row][key >> 5] >> (key & 31)) & 1;
            else      mk = Mb[(size_t)(q0 + row) * S_ + key];
            const float s = mk ? c[r] : -1e9f;
            sc[row][(((key >> 3) ^ (row & 7)) << 3) + (key & 7)] = (unsigned short)f2bf(s);
        }
    }
    __syncthreads();

    // ---- Phase 2: softmax + attn write (wave w -> rows 4w..4w+3) ----
    #pragma unroll
    for (int r = 0; r < 4; ++r) {
        const int q = w * 4 + r;
        const int x = q & 7;
        float f[32];
        #pragma unroll
        for (int i = 0; i < 4; ++i) {
            const u16x8 u = *(const u16x8*)&sc[q][(i * 64 + l) * 8];
            #pragma unroll
            for (int j = 0; j < 8; ++j) f[i * 8 + j] = bf2f(u[j]);
        }
        float m = f[0];
        #pragma unroll
        for (int j = 1; j < 32; ++j) m = fmaxf(m, f[j]);
        #pragma unroll
        for (int off = 32; off; off >>= 1) m = fmaxf(m, __shfl_xor(m, off));
        float ssum = 0.f;
        #pragma unroll
        for (int j = 0; j < 32; ++j) { f[j] = __expf(f[j] - m); ssum += f[j]; }
        #pragma unroll
        for (int off = 32; off; off >>= 1) ssum += __shfl_xor(ssum, off);
        const float il = 1.0f / ssum;
        if (l == 0) linv[q] = il;

        float* arow = attn_out + ((size_t)bh * S_ + q0 + q) * S_;
        #pragma unroll
        for (int i = 0; i < 4; ++i) {
            const int us = i * 64 + l;              // storage unit (swizzled domain)
            u16x8 ub;
            #pragma unroll
            for (int j = 0; j < 8; ++j) ub[j] = (unsigned short)f2bf(f[i * 8 + j]);
            *(u16x8*)&sc[q][us * 8] = ub;           // exp (unnormalized) for PV
            const int uk = us ^ x;                  // key unit in global order
            float4 o0, o1;
            o0.x = f[i*8+0]*il; o0.y = f[i*8+1]*il; o0.z = f[i*8+2]*il; o0.w = f[i*8+3]*il;
            o1.x = f[i*8+4]*il; o1.y = f[i*8+5]*il; o1.z = f[i*8+6]*il; o1.w = f[i*8+7]*il;
            *(float4*)(arow + (size_t)uk * 8)     = o0;
            *(float4*)(arow + (size_t)uk * 8 + 4) = o1;
        }
    }
    __syncthreads();

    // ---- Phase 3: PV (wave w -> d-tile [16w,16w+16)) ----
    {
        const int d0 = w * 16;
        f32x4 cc = {0.f, 0.f, 0.f, 0.f};
        #pragma unroll 2
        for (int ks = 0; ks < 64; ++ks) {
            const int k0 = ks * 32;
            const int un = ((k0 >> 3) + lg) ^ (lr & 7);
            const bf16x8 pa = *(const bf16x8*)&sc[lr][un * 8];     // A: P[q=lr][k]
            bf16x8 vb;
            if (PREP) {
                vb = *(const bf16x8*)(Vt + ((size_t)bh * D_ + d0 + lr) * S_ + k0 + lg * 8);
            } else {
                const float* vp = V + ((size_t)bh * S_ + k0 + lg * 8) * D_ + d0 + lr;
                #pragma unroll
                for (int j = 0; j < 8; ++j) vb[j] = f2bf(vp[(size_t)j * D_]);
            }
            cc = __builtin_amdgcn_mfma_f32_16x16x32_bf16(pa, vb, cc, 0, 0, 0);
        }
        #pragma unroll
        for (int r = 0; r < 4; ++r) {
            const int q = lg * 4 + r;
            ctx_out[((size_t)bh * S_ + q0 + q) * D_ + d0 + lr] = cc[r] * linv[q];
        }
    }
}

extern "C" void kernel_launch(void* const* d_in, const int* in_sizes, int n_in,
                              void* d_out, int out_size, void* d_ws, size_t ws_size,
                              hipStream_t stream) {
    const float* Q = (const float*)d_in[0];
    const float* K = (const float*)d_in[1];
    const float* V = (const float*)d_in[2];
    const int*   M = (const int*)d_in[3];

    float* ctx  = (float*)d_out;
    float* attn = (float*)d_out + (size_t)B_ * H_ * S_ * D_;

    const size_t nEl      = (size_t)B_ * H_ * S_ * D_;        // 4.19M
    const size_t nBits64  = (size_t)B_ * S_ * (S_ / 64);      // 131072
    const size_t need     = nEl * 2 * 2 + nBits64 * 8;        // ~17.8 MB

    if (ws_size >= need) {
        unsigned short* Kb = (unsigned short*)d_ws;
        unsigned short* Vt = Kb + nEl;
        unsigned long long* bits = (unsigned long long*)(Vt + nEl);
        cvtK_kernel    <<<dim3((int)(nEl / 2048)), dim3(256), 0, stream>>>(K, Kb);
        cvtVT_kernel   <<<dim3(B_ * H_ * (S_ / 32)), dim3(256), 0, stream>>>(V, Vt);
        maskbits_kernel<<<dim3((int)(nBits64 / 128)), dim3(256), 0, stream>>>(M, bits);
        sdpa_mfma_kernel<1><<<dim3(NBLK), dim3(256), 0, stream>>>(
            Q, K, V, M, Kb, Vt, (const unsigned*)bits, ctx, attn);
    } else {
        sdpa_mfma_kernel<0><<<dim3(NBLK), dim3(256), 0, stream>>>(
            Q, K, V, M, nullptr, nullptr, nullptr, ctx, attn);
    }
}